// Round 8
// baseline (46.730 us; speedup 1.0000x reference)
//
#include <hip/hip_runtime.h>
#include <hip/hip_bf16.h>

// Masked SDPA, B=16, NQ=NKV=2048, D=64, f32 in/out, bf16 MFMA compute.
// R8: 32x32x16 MFMA structure (m214-style). Wave = 32 q-rows. Swapped QK^T
// (S^T: lane owns q=lane&31, kv rows in regs) -> softmax 31 in-lane ops +
// 1 shuffle; P stays IN REGISTERS: 16 v_cvt_pk_bf16_f32 + 8
// v_permlane32_swap_b32 build PV A-fragments directly (T12). No P-LDS, no
// lgkmcnt drain. Block = 8 waves = 4 qsub x 2 kv-halves (128 q rows), grid
// 256 (1 block/CU). Counted-vmcnt K/V double-buffer kept (T3/T4). Prep pass
// unchanged: K/V -> bf16 swizzled LDS-image layouts in d_ws.

typedef __attribute__((ext_vector_type(8))) short short8;
typedef __attribute__((ext_vector_type(4))) short short4v;
typedef __attribute__((ext_vector_type(4))) float float4v;
typedef __attribute__((ext_vector_type(16))) float f32x16;

#define BATCH 16
#define NQ 2048
#define NKV 2048
#define DH 64
#define KVB 64
#define NTILES (NKV / KVB)          // 32
#define TILE_ELEMS (KVB * DH)       // 4096 bf16 = 8 KB
#define NEG_INF -1e20f
// (1/sqrt(64)) * log2(e)
#define SCALE_LOG2 0.180336880111120f

__device__ __forceinline__ short f2bf(float x) {
    union { float f; unsigned u; } v; v.f = x;
    unsigned r = (v.u + 0x7fffu + ((v.u >> 16) & 1u)) >> 16;
    return (short)r;
}

__device__ __forceinline__ short8 cvt8(float4v a, float4v b) {
    short8 r;
    r[0] = f2bf(a[0]); r[1] = f2bf(a[1]); r[2] = f2bf(a[2]); r[3] = f2bf(a[3]);
    r[4] = f2bf(b[0]); r[5] = f2bf(b[1]); r[6] = f2bf(b[2]); r[7] = f2bf(b[3]);
    return r;
}

// async global->LDS, 16B/lane (dest = wave-uniform base + lane*16)
__device__ __forceinline__ void gll16(const short* g, short* l) {
    __builtin_amdgcn_global_load_lds(
        (const __attribute__((address_space(1))) unsigned int*)g,
        (__attribute__((address_space(3))) unsigned int*)l, 16, 0, 0);
}

// ---------------- prep: f32 -> bf16, LDS-image layouts in ws ----------------
__global__ __launch_bounds__(256) void prep_kernel(
    const float* __restrict__ K, const float* __restrict__ V,
    const int* __restrict__ valid_lens,
    short* __restrict__ Kws, short* __restrict__ Vws)
{
    const int b    = blockIdx.x >> 5;
    const int tile = blockIdx.x & 31;
    const int vlen = valid_lens[b];
    const int nkv  = (vlen == 0) ? NKV : vlen;
    if (tile * KVB >= nkv) return;          // never read by attn

    const int tid = threadIdx.x;
    const size_t gbase = ((size_t)b * NKV + (size_t)tile * KVB) * DH;
    short* kt = Kws + (((size_t)b * NTILES + tile) * TILE_ELEMS);
    short* vt = Vws + (((size_t)b * NTILES + tile) * TILE_ELEMS);

    {   // K: row-major [kv][d], col XOR-swizzled by (row&7)<<3
        const int row = tid >> 2;
        const int col = (tid & 3) << 4;
        const float* p = K + gbase + (size_t)row * DH + col;
        float4v a0 = *reinterpret_cast<const float4v*>(p);
        float4v a1 = *reinterpret_cast<const float4v*>(p + 4);
        float4v a2 = *reinterpret_cast<const float4v*>(p + 8);
        float4v a3 = *reinterpret_cast<const float4v*>(p + 12);
        const int sw = (row & 7) << 3;
        *reinterpret_cast<short8*>(&kt[row * DH + (col ^ sw)])       = cvt8(a0, a1);
        *reinterpret_cast<short8*>(&kt[row * DH + ((col + 8) ^ sw)]) = cvt8(a2, a3);
    }
    {   // V: transposed [d][kv], kv XOR-swizzled by (d&7)<<3
        const int kv = (tid >> 4) << 2;
        const int d  = (tid & 15) << 2;
        const float* p = V + gbase + (size_t)kv * DH + d;
        float4v r0 = *reinterpret_cast<const float4v*>(p);
        float4v r1 = *reinterpret_cast<const float4v*>(p + DH);
        float4v r2 = *reinterpret_cast<const float4v*>(p + 2 * DH);
        float4v r3 = *reinterpret_cast<const float4v*>(p + 3 * DH);
#pragma unroll
        for (int k = 0; k < 4; ++k) {
            const int dd = d + k;
            short4v w;
            w[0] = f2bf(r0[k]); w[1] = f2bf(r1[k]);
            w[2] = f2bf(r2[k]); w[3] = f2bf(r3[k]);
            *reinterpret_cast<short4v*>(
                &vt[dd * KVB + (kv ^ ((dd & 7) << 3))]) = w;
        }
    }
}

// ------------- attn: 8 waves = 4 qsub(32 q-rows) x 2 KV halves -------------
__global__ __launch_bounds__(512) void attn_fwd_kernel(
    const float* __restrict__ Q,
    const short* __restrict__ Kws,
    const short* __restrict__ Vws,
    const int* __restrict__ valid_lens,
    float* __restrict__ O)
{
    __shared__ __align__(16) short k_lds[2][2][TILE_ELEMS];  // [buf][half]
    __shared__ __align__(16) short v_lds[2][2][TILE_ELEMS];  // [buf][half]

    const int tid  = threadIdx.x;
    const int wave = tid >> 6;
    const int lane = tid & 63;
    const int l31  = lane & 31;
    const int hi   = lane >> 5;
    const int l7   = lane & 7;
    const int h    = wave >> 2;            // KV half
    const int qsub = wave & 3;             // q sub-tile (32 rows)

    const int b  = blockIdx.x & 15;        // 256 blocks: 1/CU; batch's 16
    const int qt = blockIdx.x >> 4;        // blocks share an XCD (L2 locality)
    const int qbase = qt * 128 + qsub * 32;

    const int vlen  = valid_lens[b];
    const int nkv   = (vlen == 0) ? NKV : vlen;
    const int tiles = (nkv + KVB - 1) / KVB;
    const int nh = (tiles + 1 - h) >> 1;   // my half's tile count (interleaved)
    const int n0 = (tiles + 1) >> 1;

    // Q B-fragments (scale folded): lane col q=l31, k-elems d = kk*16+hi*8+j
    const float* Qb = Q + ((size_t)b * NQ + qbase + l31) * DH;
    short8 qfrag[4];
#pragma unroll
    for (int kk = 0; kk < 4; ++kk) {
        const float* p = Qb + kk * 16 + hi * 8;
        float4v a = *reinterpret_cast<const float4v*>(p);
        float4v c = *reinterpret_cast<const float4v*>(p + 4);
#pragma unroll
        for (int j = 0; j < 4; ++j) { a[j] *= SCALE_LOG2; c[j] *= SCALE_LOG2; }
        qfrag[kk] = cvt8(a, c);
    }

    const short* Kb = Kws + (size_t)b * NTILES * TILE_ELEMS;
    const short* Vb = Vws + (size_t)b * NTILES * TILE_ELEMS;
    const int soff = qsub * 1024 + lane * 8;   // wave covers 1/4 of half-tile

    auto stage = [&](int buf, int tile) {
        const short* kp = Kb + (size_t)tile * TILE_ELEMS;
        const short* vp = Vb + (size_t)tile * TILE_ELEMS;
        gll16(kp + soff,       &k_lds[buf][h][soff]);
        gll16(kp + soff + 512, &k_lds[buf][h][soff + 512]);
        gll16(vp + soff,       &v_lds[buf][h][soff]);
        gll16(vp + soff + 512, &v_lds[buf][h][soff + 512]);
    };

    f32x16 acc_o[2];
#pragma unroll
    for (int t = 0; t < 2; ++t)
#pragma unroll
        for (int r = 0; r < 16; ++r) acc_o[t][r] = 0.f;
    float m = -INFINITY, lsum = 0.f;

    if (nh > 0) stage(0, h);

    for (int it = 0; it < n0; ++it) {
        const int cur = it & 1;
        if (it + 1 < nh) {
            stage(cur ^ 1, 2 * (it + 1) + h);
            asm volatile("s_waitcnt vmcnt(4)" ::: "memory");  // tile-it done
        } else {
            asm volatile("s_waitcnt vmcnt(0)" ::: "memory");
        }
        __builtin_amdgcn_s_barrier();
        asm volatile("" ::: "memory");

        if (it < nh) {
            const int tile = 2 * it + h;
            const short* kds = k_lds[cur][h];
            const short* vds = v_lds[cur][h];

            // ---- S^T = K Q^T: lane owns q=l31, kv = 32s + (r&3)+8(r>>2)+4hi
            f32x16 acs[2];
#pragma unroll
            for (int s = 0; s < 2; ++s)
#pragma unroll
                for (int r = 0; r < 16; ++r) acs[s][r] = 0.f;
            __builtin_amdgcn_s_setprio(1);
#pragma unroll
            for (int s = 0; s < 2; ++s)
#pragma unroll
                for (int kk = 0; kk < 4; ++kk) {
                    short8 kf = *reinterpret_cast<const short8*>(
                        &kds[(s * 32 + l31) * DH + ((kk * 16 + hi * 8) ^ (l7 * 8))]);
                    acs[s] = __builtin_amdgcn_mfma_f32_32x32x16_bf16(
                        kf, qfrag[kk], acs[s], 0, 0, 0);
                }
            __builtin_amdgcn_s_setprio(0);

            // ---- mask (log2 units already) ----
            const int kvb0 = tile * KVB + 4 * hi;
#pragma unroll
            for (int s = 0; s < 2; ++s) {
                const int vlim = vlen - (kvb0 + s * 32);
#pragma unroll
                for (int r = 0; r < 16; ++r) {
                    const int rc = (r & 3) + 8 * (r >> 2);
                    acs[s][r] = (rc < vlim) ? acs[s][r] : NEG_INF;
                }
            }

            // ---- row max: 31 in-lane + 1 shuffle ----
            float x = acs[0][0];
#pragma unroll
            for (int r = 1; r < 16; ++r) x = fmaxf(x, acs[0][r]);
#pragma unroll
            for (int r = 0; r < 16; ++r) x = fmaxf(x, acs[1][r]);
            x = fmaxf(x, __shfl_xor(x, 32, 64));

            // ---- T13 defer-max ----
            float mn = m;
            if (!__all(x <= m + 8.f)) {
                mn = fmaxf(m, x);
                const float alpha = exp2f(m - mn);   // m=-inf first -> 0
                m = mn;
                lsum *= alpha;
#pragma unroll
                for (int r = 0; r < 16; ++r) {
                    const int rc = (r & 3) + 8 * (r >> 2);
                    const float ar = __shfl(alpha, rc + 4 * hi, 64);
                    acc_o[0][r] *= ar;
                    acc_o[1][r] *= ar;
                }
            }

            // ---- P = exp2(s - mn), in-lane sum + 1 shuffle ----
            float rs = 0.f;
#pragma unroll
            for (int s = 0; s < 2; ++s)
#pragma unroll
                for (int r = 0; r < 16; ++r) {
                    const float p = exp2f(acs[s][r] - mn);
                    acs[s][r] = p;
                    rs += p;
                }
            rs += __shfl_xor(rs, 32, 64);
            lsum += rs;

            // ---- preload V fragments (overlap ds latency with packing) ----
            short8 vf[2][4];
#pragma unroll
            for (int t = 0; t < 2; ++t)
#pragma unroll
                for (int ks = 0; ks < 4; ++ks)
                    vf[t][ks] = *reinterpret_cast<const short8*>(
                        &vds[(t * 32 + l31) * DH + ((ks * 16 + hi * 8) ^ (l7 * 8))]);

            // ---- P -> bf16 packs (T12): 16 cvt_pk ----
            unsigned pk[2][4][2];
#pragma unroll
            for (int s = 0; s < 2; ++s)
#pragma unroll
                for (int be = 0; be < 4; ++be)
#pragma unroll
                    for (int c = 0; c < 2; ++c)
                        asm("v_cvt_pk_bf16_f32 %0, %1, %2"
                            : "=v"(pk[s][be][c])
                            : "v"(acs[s][4 * be + 2 * c]),
                              "v"(acs[s][4 * be + 2 * c + 1]));

            // ---- O += P V: 8 permlane32_swap build A-frags in-register ----
            __builtin_amdgcn_s_setprio(1);
#pragma unroll
            for (int ks = 0; ks < 4; ++ks) {
                const int s = ks >> 1, g = ks & 1;
                unsigned w0 = pk[s][2 * g][0], w2 = pk[s][2 * g + 1][0];
                unsigned w1 = pk[s][2 * g][1], w3 = pk[s][2 * g + 1][1];
                asm("v_permlane32_swap_b32 %0, %1" : "+v"(w0), "+v"(w2));
                asm("v_permlane32_swap_b32 %0, %1" : "+v"(w1), "+v"(w3));
                union { unsigned u[4]; short8 s8; } pf;
                pf.u[0] = w0; pf.u[1] = w1; pf.u[2] = w2; pf.u[3] = w3;
#pragma unroll
                for (int t = 0; t < 2; ++t)
                    acc_o[t] = __builtin_amdgcn_mfma_f32_32x32x16_bf16(
                        pf.s8, vf[t][ks], acc_o[t], 0, 0, 0);
            }
            __builtin_amdgcn_s_setprio(0);
        }

        asm volatile("" ::: "memory");
        __builtin_amdgcn_s_barrier();      // buf cur free at it+2
    }

    // ---- merge the two KV halves; reuse k_lds (acc) / v_lds (m,l) ----
    float*  mrg = reinterpret_cast<float*>(k_lds);   // 4 qsub x 2048 f32
    float2* mlb = reinterpret_cast<float2*>(v_lds);
    if (h == 1) {
#pragma unroll
        for (int t = 0; t < 2; ++t)
#pragma unroll
            for (int r = 0; r < 16; ++r)
                mrg[qsub * 2048 + (t * 16 + r) * 64 + lane] = acc_o[t][r];
        if (lane < 32) mlb[qsub * 32 + lane] = float2{m, lsum};
    }
    __syncthreads();
    if (h == 0) {
        const float2 o1 = mlb[qsub * 32 + l31];
        const float m1 = o1.x, l1 = o1.y;
        const float M  = (l1 > 0.f) ? fmaxf(m, m1) : m;
        const float w0 = exp2f(m - M);
        const float w1 = (l1 > 0.f) ? exp2f(m1 - M) : 0.f;
        const float L  = lsum * w0 + l1 * w1;
        const float a0 = w0 / L, a1 = w1 / L;
        float* Ob = O + ((size_t)b * NQ + qbase) * DH;
#pragma unroll
        for (int r = 0; r < 16; ++r) {
            const int rc = (r & 3) + 8 * (r >> 2);
            const float a0r = __shfl(a0, rc + 4 * hi, 64);
            const float a1r = __shfl(a1, rc + 4 * hi, 64);
#pragma unroll
            for (int t = 0; t < 2; ++t) {
                const float oh = mrg[qsub * 2048 + (t * 16 + r) * 64 + lane];
                Ob[(size_t)(rc + 4 * hi) * DH + t * 32 + l31] =
                    acc_o[t][r] * a0r + oh * a1r;
            }
        }
    }
}

extern "C" void kernel_launch(void* const* d_in, const int* in_sizes, int n_in,
                              void* d_out, int out_size, void* d_ws, size_t ws_size,
                              hipStream_t stream) {
    const float* Q = (const float*)d_in[0];
    const float* K = (const float*)d_in[1];
    const float* V = (const float*)d_in[2];
    const int* vl  = (const int*)d_in[3];
    float* Out     = (float*)d_out;

    short* Kws = (short*)d_ws;
    short* Vws = Kws + (size_t)BATCH * NTILES * TILE_ELEMS;

    prep_kernel<<<dim3(BATCH * NTILES), dim3(256), 0, stream>>>(K, V, vl, Kws, Vws);
    attn_fwd_kernel<<<dim3(BATCH * (NQ / 128)), dim3(512), 0, stream>>>(
        Q, Kws, Vws, vl, Out);
}

// Round 9
// 43.852 us; speedup vs baseline: 1.0656x; 1.0656x over previous
//
#include <hip/hip_runtime.h>
#include <hip/hip_bf16.h>

// Masked SDPA, B=16, NQ=NKV=2048, D=64, f32 in/out, bf16 MFMA compute.
// R9: barrier-free, LDS-free main loop. Prep writes K/V as fragment-
// sequential bf16 layouts ([tile][frag][lane] 16B) so every MFMA operand is
// one coalesced 1KB global load served by L1/L2 (K/V ws = 16 MB, cache-
// resident; staging was pure overhead per guide mistake #7 / m169).
// Per-wave software pipeline: V(cur) issued before QK^T, K(next) into the
// alternate reg buffer mid-tile. Softmax max/sum as depth-5 trees. 32x32
// swapped-QK^T + in-register P (cvt_pk + permlane32_swap) from R8. Halves
// merged in a small dedicated LDS buffer at the end (one syncthreads).

typedef __attribute__((ext_vector_type(8))) short short8;
typedef __attribute__((ext_vector_type(4))) float float4v;
typedef __attribute__((ext_vector_type(16))) float f32x16;

#define BATCH 16
#define NQ 2048
#define NKV 2048
#define DH 64
#define KVB 64
#define NTILES (NKV / KVB)          // 32
#define TILE_ELEMS (KVB * DH)       // 4096 bf16 = 8 KB per tile per array
#define NEG_INF -1e20f
// (1/sqrt(64)) * log2(e)
#define SCALE_LOG2 0.180336880111120f

__device__ __forceinline__ short f2bf(float x) {
    union { float f; unsigned u; } v; v.f = x;
    unsigned r = (v.u + 0x7fffu + ((v.u >> 16) & 1u)) >> 16;
    return (short)r;
}

__device__ __forceinline__ short8 cvt8(float4v a, float4v b) {
    short8 r;
    r[0] = f2bf(a[0]); r[1] = f2bf(a[1]); r[2] = f2bf(a[2]); r[3] = f2bf(a[3]);
    r[4] = f2bf(b[0]); r[5] = f2bf(b[1]); r[6] = f2bf(b[2]); r[7] = f2bf(b[3]);
    return r;
}

// ---- prep v2: f32 -> bf16 fragment-sequential layouts -----------------------
// Kf[b][tile][s*4+kk][lane] : lane(l31,hi) holds K[kv=s*32+l31][d=kk*16+hi*8..+7]
// Vf[b][tile][t*4+ks][lane] : lane(l31,hi) holds V^T[d=t*32+l31][kv=ks*16+hi*8..+7]
__global__ __launch_bounds__(256) void prep_kernel(
    const float* __restrict__ K, const float* __restrict__ V,
    const int* __restrict__ valid_lens,
    short* __restrict__ Kf, short* __restrict__ Vf)
{
    const int b    = blockIdx.x >> 5;
    const int tile = blockIdx.x & 31;
    const int vlen = valid_lens[b];
    const int nkv  = (vlen == 0) ? NKV : vlen;
    if (tile * KVB >= nkv) return;          // never read by attn

    const int tid = threadIdx.x;
    const int ln  = tid & 63;
    const int l31 = ln & 31;
    const int hi8 = (ln >> 5) * 8;
    const size_t gbase = ((size_t)b * NKV + (size_t)tile * KVB) * DH;
    short* kt = Kf + (((size_t)b * NTILES + tile) * TILE_ELEMS);
    short* vt = Vf + (((size_t)b * NTILES + tile) * TILE_ELEMS);

#pragma unroll
    for (int s = 0; s < 2; ++s) {           // K frags: slots s*256+tid
        const int kk = tid >> 6;            // 0..3
        const int kv = s * 32 + l31;
        const int d  = kk * 16 + hi8;
        const float* p = K + gbase + (size_t)kv * DH + d;
        *reinterpret_cast<short8*>(kt + (s * 256 + tid) * 8) =
            cvt8(*reinterpret_cast<const float4v*>(p),
                 *reinterpret_cast<const float4v*>(p + 4));
    }
#pragma unroll
    for (int t = 0; t < 2; ++t) {           // V frags: slots t*256+tid
        const int ks  = tid >> 6;           // 0..3
        const int d   = t * 32 + l31;
        const int kv0 = ks * 16 + hi8;
        short8 w;
#pragma unroll
        for (int j = 0; j < 8; ++j)
            w[j] = f2bf(V[gbase + (size_t)(kv0 + j) * DH + d]);
        *reinterpret_cast<short8*>(vt + (t * 256 + tid) * 8) = w;
    }
}

// ------------- attn: 8 waves = 4 qsub(32 q-rows) x 2 KV halves --------------
__global__ __launch_bounds__(512) void attn_fwd_kernel(
    const float* __restrict__ Q,
    const short* __restrict__ Kf,
    const short* __restrict__ Vf,
    const int* __restrict__ valid_lens,
    float* __restrict__ O)
{
    __shared__ float  mrg[4][2048];        // halves merge (32 KB)
    __shared__ float2 mlb[4][32];

    const int tid  = threadIdx.x;
    const int wave = tid >> 6;
    const int lane = tid & 63;
    const int l31  = lane & 31;
    const int hi   = lane >> 5;
    const int h    = wave >> 2;            // KV half
    const int qsub = wave & 3;             // q sub-tile (32 rows)

    const int b  = blockIdx.x & 15;        // batch's 16 blocks -> same XCD L2
    const int qt = blockIdx.x >> 4;
    const int qbase = qt * 128 + qsub * 32;

    const int vlen  = valid_lens[b];
    const int nkv   = (vlen == 0) ? NKV : vlen;
    const int tiles = (nkv + KVB - 1) / KVB;
    const int nh = (tiles + 1 - h) >> 1;   // my half's tiles (interleaved)

    // Q B-fragments (scale folded): lane col q=l31, k-elems d = kk*16+hi*8+j
    const float* Qb = Q + ((size_t)b * NQ + qbase + l31) * DH;
    short8 qfrag[4];
#pragma unroll
    for (int kk = 0; kk < 4; ++kk) {
        const float* p = Qb + kk * 16 + hi * 8;
        float4v a = *reinterpret_cast<const float4v*>(p);
        float4v c = *reinterpret_cast<const float4v*>(p + 4);
#pragma unroll
        for (int j = 0; j < 4; ++j) { a[j] *= SCALE_LOG2; c[j] *= SCALE_LOG2; }
        qfrag[kk] = cvt8(a, c);
    }

    const short* Kfb = Kf + (size_t)b * NTILES * TILE_ELEMS + lane * 8;
    const short* Vfb = Vf + (size_t)b * NTILES * TILE_ELEMS + lane * 8;

    auto load_k = [&](short8 (&kf)[8], int tile) {
        const short* p = Kfb + (size_t)tile * TILE_ELEMS;
#pragma unroll
        for (int i = 0; i < 8; ++i)
            kf[i] = *reinterpret_cast<const short8*>(p + i * 512);
    };
    auto load_v = [&](short8 (&vf)[8], int tile) {
        const short* p = Vfb + (size_t)tile * TILE_ELEMS;
#pragma unroll
        for (int i = 0; i < 8; ++i)
            vf[i] = *reinterpret_cast<const short8*>(p + i * 512);
    };

    f32x16 acc_o[2];
#pragma unroll
    for (int t = 0; t < 2; ++t)
#pragma unroll
        for (int r = 0; r < 16; ++r) acc_o[t][r] = 0.f;
    float m = -INFINITY, lsum = 0.f;

    short8 kf0[8], kf1[8], vfr[8];

    auto body = [&](short8 (&kc)[8], short8 (&kn)[8], int it) {
        const int tile = 2 * it + h;
        load_v(vfr, tile);                 // issue early; used after softmax

        // ---- S^T = K Q^T: lane owns q=l31, kv = 32s + (r&3)+8(r>>2)+4hi ----
        f32x16 acs[2];
#pragma unroll
        for (int s = 0; s < 2; ++s)
#pragma unroll
            for (int r = 0; r < 16; ++r) acs[s][r] = 0.f;
        __builtin_amdgcn_s_setprio(1);
#pragma unroll
        for (int s = 0; s < 2; ++s)
#pragma unroll
            for (int kk = 0; kk < 4; ++kk)
                acs[s] = __builtin_amdgcn_mfma_f32_32x32x16_bf16(
                    kc[s * 4 + kk], qfrag[kk], acs[s], 0, 0, 0);
        __builtin_amdgcn_s_setprio(0);

        if (it + 1 < nh) load_k(kn, 2 * (it + 1) + h);  // prefetch next K

        // ---- mask (log2 units already) ----
        const int kvb0 = tile * KVB + 4 * hi;
#pragma unroll
        for (int s = 0; s < 2; ++s) {
            const int vlim = vlen - (kvb0 + s * 32);
#pragma unroll
            for (int r = 0; r < 16; ++r) {
                const int rc = (r & 3) + 8 * (r >> 2);
                acs[s][r] = (rc < vlim) ? acs[s][r] : NEG_INF;
            }
        }

        // ---- row max: depth-5 tree + 1 shuffle ----
        float mx[8];
#pragma unroll
        for (int r = 0; r < 8; ++r)
            mx[r] = fmaxf(fmaxf(acs[0][r], acs[0][r + 8]),
                          fmaxf(acs[1][r], acs[1][r + 8]));
#pragma unroll
        for (int d = 4; d; d >>= 1)
#pragma unroll
            for (int r = 0; r < d; ++r) mx[r] = fmaxf(mx[r], mx[r + d]);
        float x = mx[0];
        x = fmaxf(x, __shfl_xor(x, 32, 64));

        // ---- T13 defer-max ----
        float mn = m;
        if (!__all(x <= m + 8.f)) {
            mn = fmaxf(m, x);
            const float alpha = exp2f(m - mn);   // m=-inf first -> 0
            m = mn;
            lsum *= alpha;
#pragma unroll
            for (int r = 0; r < 16; ++r) {
                const int rc = (r & 3) + 8 * (r >> 2);
                const float ar = __shfl(alpha, rc + 4 * hi, 64);
                acc_o[0][r] *= ar;
                acc_o[1][r] *= ar;
            }
        }

        // ---- P = exp2(s - mn); sum as tree + 1 shuffle ----
#pragma unroll
        for (int s = 0; s < 2; ++s)
#pragma unroll
            for (int r = 0; r < 16; ++r) acs[s][r] = exp2f(acs[s][r] - mn);
        float sm[8];
#pragma unroll
        for (int r = 0; r < 8; ++r)
            sm[r] = (acs[0][r] + acs[0][r + 8]) + (acs[1][r] + acs[1][r + 8]);
#pragma unroll
        for (int d = 4; d; d >>= 1)
#pragma unroll
            for (int r = 0; r < d; ++r) sm[r] += sm[r + d];
        float rs = sm[0];
        rs += __shfl_xor(rs, 32, 64);
        lsum += rs;

        // ---- P -> bf16 packs (16 cvt_pk) ----
        unsigned pk[2][4][2];
#pragma unroll
        for (int s = 0; s < 2; ++s)
#pragma unroll
            for (int be = 0; be < 4; ++be)
#pragma unroll
                for (int c = 0; c < 2; ++c)
                    asm("v_cvt_pk_bf16_f32 %0, %1, %2"
                        : "=v"(pk[s][be][c])
                        : "v"(acs[s][4 * be + 2 * c]),
                          "v"(acs[s][4 * be + 2 * c + 1]));

        // ---- O += P V: 8 permlane32_swap build A-frags in-register ----
        __builtin_amdgcn_s_setprio(1);
#pragma unroll
        for (int ks = 0; ks < 4; ++ks) {
            const int s = ks >> 1, g = ks & 1;
            unsigned w0 = pk[s][2 * g][0], w2 = pk[s][2 * g + 1][0];
            unsigned w1 = pk[s][2 * g][1], w3 = pk[s][2 * g + 1][1];
            asm("v_permlane32_swap_b32 %0, %1" : "+v"(w0), "+v"(w2));
            asm("v_permlane32_swap_b32 %0, %1" : "+v"(w1), "+v"(w3));
            union { unsigned u[4]; short8 s8; } pf;
            pf.u[0] = w0; pf.u[1] = w1; pf.u[2] = w2; pf.u[3] = w3;
#pragma unroll
            for (int t = 0; t < 2; ++t)
                acc_o[t] = __builtin_amdgcn_mfma_f32_32x32x16_bf16(
                    pf.s8, vfr[t * 4 + ks], acc_o[t], 0, 0, 0);
        }
        __builtin_amdgcn_s_setprio(0);
    };

    if (nh > 0) load_k(kf0, h);
    int it = 0;
    for (; it + 1 < nh; it += 2) {         // 2-phase unroll: static reg buffers
        body(kf0, kf1, it);
        body(kf1, kf0, it + 1);
    }
    if (it < nh) body(kf0, kf1, it);

    // ---- merge the two KV halves; h==0 writes output ----
    if (h == 1) {
#pragma unroll
        for (int t = 0; t < 2; ++t)
#pragma unroll
            for (int r = 0; r < 16; ++r)
                mrg[qsub][(t * 16 + r) * 64 + lane] = acc_o[t][r];
        if (lane < 32) mlb[qsub][lane] = float2{m, lsum};
    }
    __syncthreads();
    if (h == 0) {
        const float2 o1 = mlb[qsub][l31];
        const float m1 = o1.x, l1 = o1.y;
        const float M  = (l1 > 0.f) ? fmaxf(m, m1) : m;
        const float w0 = exp2f(m - M);
        const float w1 = (l1 > 0.f) ? exp2f(m1 - M) : 0.f;
        const float L  = lsum * w0 + l1 * w1;
        const float a0 = w0 / L, a1 = w1 / L;
        float* Ob = O + ((size_t)b * NQ + qbase) * DH;
#pragma unroll
        for (int r = 0; r < 16; ++r) {
            const int rc = (r & 3) + 8 * (r >> 2);
            const float a0r = __shfl(a0, rc + 4 * hi, 64);
            const float a1r = __shfl(a1, rc + 4 * hi, 64);
#pragma unroll
            for (int t = 0; t < 2; ++t) {
                const float oh = mrg[qsub][(t * 16 + r) * 64 + lane];
                Ob[(size_t)(rc + 4 * hi) * DH + t * 32 + l31] =
                    acc_o[t][r] * a0r + oh * a1r;
            }
        }
    }
}

extern "C" void kernel_launch(void* const* d_in, const int* in_sizes, int n_in,
                              void* d_out, int out_size, void* d_ws, size_t ws_size,
                              hipStream_t stream) {
    const float* Q = (const float*)d_in[0];
    const float* K = (const float*)d_in[1];
    const float* V = (const float*)d_in[2];
    const int* vl  = (const int*)d_in[3];
    float* Out     = (float*)d_out;

    short* Kws = (short*)d_ws;
    short* Vws = Kws + (size_t)BATCH * NTILES * TILE_ELEMS;

    prep_kernel<<<dim3(BATCH * NTILES), dim3(256), 0, stream>>>(K, V, vl, Kws, Vws);
    attn_fwd_kernel<<<dim3(BATCH * (NQ / 128)), dim3(512), 0, stream>>>(
        Q, Kws, Vws, vl, Out);
}